// Round 2
// baseline (8968.250 us; speedup 1.0000x reference)
//
#include <hip/hip_runtime.h>
#include <math.h>

#define BB 4096
#define TT 5
#define KK 4
#define NLANES 12
#define GH 64
#define GO 32
#define GAT_TOT 256
#define SAGE_H 64
#define GRU_H 32

// ---------------------------------------------------------------------------
// Kernel A: per (b,t) block. GAT for self + 4 neighbors with weights held in
// registers; Wh accumulator never leaves VGPRs; LN via wave shuffles.
// ---------------------------------------------------------------------------
__global__ __launch_bounds__(256, 4) void gat_sage_kernel(
    const float* __restrict__ selfF, const float* __restrict__ nbF,
    const float* __restrict__ mask,
    const float* __restrict__ projW, const float* __restrict__ projB,
    const float* __restrict__ projG, const float* __restrict__ projBt,
    const float* __restrict__ coopW, const float* __restrict__ coopSrc, const float* __restrict__ coopDst,
    const float* __restrict__ confW, const float* __restrict__ confSrc, const float* __restrict__ confDst,
    const float* __restrict__ sageW, const float* __restrict__ sageB,
    float* __restrict__ hsage, float* __restrict__ embLast)
{
    __shared__ __align__(16) float s_x[48];
    __shared__ __align__(16) float s_h[NLANES][GH];   // 3 KB
    __shared__ float s_sd[2][8][NLANES];              // src/dst scalars
    __shared__ float s_att[8][NLANES][NLANES];        // 4.6 KB
    __shared__ float s_pool[5][GAT_TOT];              // 5 KB
    __shared__ float s_in[2 * GAT_TOT];
    __shared__ float s_part[4][SAGE_H];

    const int bid = blockIdx.x;          // b*T + t
    const int b = bid / TT, t = bid % TT;
    const int tid = threadIdx.x;

    const int gh = tid >> 5, o = tid & 31;     // thread owns (gat,head,o)
    const int g = gh >> 2, hh = gh & 3;

    // ---- hoist GAT weights into registers (reused across 5 instances) ----
    float wreg[GH];
    {
        const float* Wp = (g ? confW : coopW) + hh * GH * GO + o;
        #pragma unroll
        for (int f = 0; f < GH; ++f) wreg[f] = Wp[f * GO];
    }
    const float a_s = (g ? confSrc : coopSrc)[hh * GO + o];
    const float a_d = (g ? confDst : coopDst)[hh * GO + o];

    // ---- hoist proj row (lane-as-feature mapping: wave=wv, lane=f) ----
    const int wv = tid >> 6, f = tid & 63;
    const float pw0 = projW[0 * GH + f], pw1 = projW[1 * GH + f];
    const float pw2 = projW[2 * GH + f], pw3 = projW[3 * GH + f];
    const float pb = projB[f], pg = projG[f], pbt = projBt[f];

    for (int inst = 0; inst < 1 + KK; ++inst) {
        const float* xp = (inst == 0)
            ? (selfF + (size_t)bid * 48)
            : (nbF + (size_t)((b * KK + (inst - 1)) * TT + t) * 48);
        if (tid < 12) ((float4*)s_x)[tid] = ((const float4*)xp)[tid];
        __syncthreads();

        // ---- proj + LayerNorm + relu; wave wv handles lanes {wv, wv+4, wv+8}
        {
            float hv[3], s1[3], s2[3];
            #pragma unroll
            for (int i = 0; i < 3; ++i) {
                int n = wv + i * 4;
                float v = pb + s_x[n * 4 + 0] * pw0 + s_x[n * 4 + 1] * pw1
                             + s_x[n * 4 + 2] * pw2 + s_x[n * 4 + 3] * pw3;
                hv[i] = v; s1[i] = v; s2[i] = v * v;
            }
            #pragma unroll
            for (int m = 1; m < 64; m <<= 1) {
                #pragma unroll
                for (int i = 0; i < 3; ++i) {
                    s1[i] += __shfl_xor(s1[i], m);
                    s2[i] += __shfl_xor(s2[i], m);
                }
            }
            #pragma unroll
            for (int i = 0; i < 3; ++i) {
                float mean = s1[i] * (1.f / 64.f);
                float var  = s2[i] * (1.f / 64.f) - mean * mean;
                float rstd = rsqrtf(var + 1e-5f);
                float v = (hv[i] - mean) * rstd * pg + pbt;
                s_h[wv + i * 4][f] = fmaxf(v, 0.f);
            }
        }
        __syncthreads();

        // ---- Wh: acc[n] = sum_f h[n][f] * W[f][o] (full-wave-broadcast b128)
        float acc[NLANES];
        #pragma unroll
        for (int n = 0; n < NLANES; ++n) acc[n] = 0.f;
        #pragma unroll
        for (int fc = 0; fc < 16; ++fc) {
            #pragma unroll
            for (int n = 0; n < NLANES; ++n) {
                float4 h4 = *(const float4*)&s_h[n][fc * 4];
                acc[n] += h4.x * wreg[fc * 4 + 0] + h4.y * wreg[fc * 4 + 1]
                        + h4.z * wreg[fc * 4 + 2] + h4.w * wreg[fc * 4 + 3];
            }
        }

        // ---- attention src scalars: reduce acc[n]*a_s over the 32 o-lanes
        {
            float sp[NLANES];
            #pragma unroll
            for (int n = 0; n < NLANES; ++n) sp[n] = acc[n] * a_s;
            #pragma unroll
            for (int m = 1; m < 32; m <<= 1) {
                #pragma unroll
                for (int n = 0; n < NLANES; ++n) sp[n] += __shfl_xor(sp[n], m);
            }
            if (o == 0) {
                #pragma unroll
                for (int n = 0; n < NLANES; ++n) s_sd[0][gh][n] = sp[n];
            }
            #pragma unroll
            for (int n = 0; n < NLANES; ++n) sp[n] = acc[n] * a_d;
            #pragma unroll
            for (int m = 1; m < 32; m <<= 1) {
                #pragma unroll
                for (int n = 0; n < NLANES; ++n) sp[n] += __shfl_xor(sp[n], m);
            }
            if (o == 0) {
                #pragma unroll
                for (int n = 0; n < NLANES; ++n) s_sd[1][gh][n] = sp[n];
            }
        }
        __syncthreads();

        // ---- masked softmax rows (96 threads: gh2 x n2)
        if (tid < 96) {
            int gh2 = tid / 12, n2 = tid % 12;
            int g2 = gh2 >> 2;
            int an = n2 / 3;
            float sn = s_sd[0][gh2][n2];
            float e[NLANES];
            float mx = -1e30f;
            #pragma unroll
            for (int m2 = 0; m2 < NLANES; ++m2) {
                int am = m2 / 3;
                bool valid = (g2 == 0) ? (am == an) : (am != an || m2 == n2);
                if (valid) {
                    float ev = sn + s_sd[1][gh2][m2];
                    ev = ev > 0.f ? ev : 0.2f * ev;
                    e[m2] = ev;
                    mx = fmaxf(mx, ev);
                } else e[m2] = -1e30f;
            }
            float sum = 0.f;
            #pragma unroll
            for (int m2 = 0; m2 < NLANES; ++m2) {
                float ex = (e[m2] > -1e29f) ? expf(e[m2] - mx) : 0.f;
                e[m2] = ex; sum += ex;
            }
            float inv = 1.f / sum;
            #pragma unroll
            for (int m2 = 0; m2 < NLANES; ++m2) s_att[gh2][n2][m2] = e[m2] * inv;
        }
        __syncthreads();

        // ---- out = att @ Wh (Wh cols already in acc registers), elu, pool
        {
            float pooled = 0.f;
            #pragma unroll
            for (int n = 0; n < NLANES; ++n) {
                float v = 0.f;
                #pragma unroll
                for (int m2 = 0; m2 < NLANES; ++m2)
                    v += s_att[gh][n][m2] * acc[m2];
                v = v > 0.f ? v : expm1f(v);
                pooled += v;
            }
            s_pool[inst][tid] = pooled * (1.f / 12.f);
        }
        __syncthreads();
    }

    // ---- agg (masked mean) + concat
    {
        float m0 = mask[b * KK + 0], m1 = mask[b * KK + 1];
        float m2 = mask[b * KK + 2], m3 = mask[b * KK + 3];
        float inv = 1.f / fmaxf(m0 + m1 + m2 + m3, 1.f);
        s_in[tid] = s_pool[0][tid];
        s_in[GAT_TOT + tid] = (m0 * s_pool[1][tid] + m1 * s_pool[2][tid]
                             + m2 * s_pool[3][tid] + m3 * s_pool[4][tid]) * inv;
    }
    __syncthreads();

    // ---- central-node GraphSAGE row: split-K over 4 groups
    {
        int j = tid & 63, q = tid >> 6;
        float v = 0.f;
        for (int c = q * 128; c < q * 128 + 128; ++c)
            v += s_in[c] * sageW[c * SAGE_H + j];
        s_part[q][j] = v;
    }
    __syncthreads();
    if (tid < SAGE_H) {
        float v = sageB[tid] + s_part[0][tid] + s_part[1][tid]
                + s_part[2][tid] + s_part[3][tid];
        hsage[(size_t)bid * SAGE_H + tid] = fmaxf(v, 0.f);
    }
    if (t == TT - 1) embLast[(size_t)b * GAT_TOT + tid] = s_pool[0][tid];
}

// ---------------------------------------------------------------------------
// Kernel B: per-b block, 256 threads. Parallel gx precompute, serial h-part
// only, split-K MLP heads with shuffle LN.
// ---------------------------------------------------------------------------
__global__ __launch_bounds__(256) void gru_head_kernel(
    const float* __restrict__ hsage, const float* __restrict__ embLast,
    const float* __restrict__ gfWx, const float* __restrict__ gfWh,
    const float* __restrict__ gfbx, const float* __restrict__ gfbh,
    const float* __restrict__ gbWx, const float* __restrict__ gbWh,
    const float* __restrict__ gbbx, const float* __restrict__ gbbh,
    const float* __restrict__ pW1, const float* __restrict__ pb1,
    const float* __restrict__ pg1, const float* __restrict__ pbt1,
    const float* __restrict__ pW2, const float* __restrict__ pb2,
    const float* __restrict__ pg2, const float* __restrict__ pbt2,
    const float* __restrict__ pWo, const float* __restrict__ pbo,
    const float* __restrict__ vW1, const float* __restrict__ vb1,
    const float* __restrict__ vg1, const float* __restrict__ vbt1,
    const float* __restrict__ vW2, const float* __restrict__ vb2,
    const float* __restrict__ vg2, const float* __restrict__ vbt2,
    const float* __restrict__ vWo, const float* __restrict__ vbo,
    float* __restrict__ dout)
{
    __shared__ float s_seq[TT * SAGE_H];     // 320
    __shared__ float s_gx[2][TT][96];        // 960
    __shared__ float s_hh[2][GRU_H];
    __shared__ float s_joint[320];
    __shared__ float s_h1[128];
    __shared__ float s_h2[64];
    __shared__ float s_p1[2][128];
    __shared__ float s_p2[4][64];
    __shared__ float s_red[4];

    const int b = blockIdx.x, tid = threadIdx.x;

    for (int i = tid; i < TT * SAGE_H; i += 256) s_seq[i] = hsage[(size_t)b * TT * SAGE_H + i];
    s_joint[tid] = embLast[(size_t)b * GAT_TOT + tid];
    if (tid < 64) s_hh[tid >> 5][tid & 31] = 0.f;
    __syncthreads();

    // gx precompute: 2 dirs x 5 t x 96 gates = 960 tasks
    for (int task = tid; task < 960; task += 256) {
        int dir = task >= 480;
        int rem = task - dir * 480;
        int t5 = rem / 96, j = rem - t5 * 96;
        const float* Wx = dir ? gbWx : gfWx;
        const float* bx = dir ? gbbx : gfbx;
        const float* x = &s_seq[t5 * SAGE_H];
        float v = bx[j];
        for (int f2 = 0; f2 < SAGE_H; ++f2) v += x[f2] * Wx[f2 * 96 + j];
        s_gx[dir][t5][j] = v;
    }
    __syncthreads();

    // serial GRU (h-part only)
    for (int s = 0; s < TT; ++s) {
        float hnew = 0.f;
        if (tid < 64) {
            int dir = tid >> 5, j = tid & 31;
            int t5 = dir ? (TT - 1 - s) : s;
            const float* Wh = dir ? gbWh : gfWh;
            const float* bh = dir ? gbbh : gfbh;
            const float* h = s_hh[dir];
            float hr = bh[j], hz = bh[32 + j], hn = bh[64 + j];
            for (int k = 0; k < GRU_H; ++k) {
                float hv = h[k];
                hr += hv * Wh[k * 96 + j];
                hz += hv * Wh[k * 96 + 32 + j];
                hn += hv * Wh[k * 96 + 64 + j];
            }
            float xr = s_gx[dir][t5][j], xz = s_gx[dir][t5][32 + j], xn = s_gx[dir][t5][64 + j];
            float r = 1.f / (1.f + expf(-(xr + hr)));
            float z = 1.f / (1.f + expf(-(xz + hz)));
            float nn = tanhf(xn + r * hn);
            hnew = (1.f - z) * nn + z * h[j];
        }
        __syncthreads();
        if (tid < 64) s_hh[tid >> 5][tid & 31] = hnew;
        __syncthreads();
    }
    if (tid < 64) s_joint[GAT_TOT + tid] = s_hh[tid >> 5][tid & 31];
    __syncthreads();

    for (int hd = 0; hd < 2; ++hd) {
        const float* W1 = hd ? vW1 : pW1;  const float* b1 = hd ? vb1 : pb1;
        const float* g1 = hd ? vg1 : pg1;  const float* bt1 = hd ? vbt1 : pbt1;
        const float* W2 = hd ? vW2 : pW2;  const float* b2 = hd ? vb2 : pb2;
        const float* g2 = hd ? vg2 : pg2;  const float* bt2 = hd ? vbt2 : pbt2;
        const float* Wo = hd ? vWo : pWo;  const float* bo = hd ? vbo : pbo;

        // W1: 320x128, split-K over 2 halves
        {
            int j = tid & 127, hf = tid >> 7;
            float v = (hf == 0) ? b1[j] : 0.f;
            for (int c = hf * 160; c < hf * 160 + 160; ++c)
                v += s_joint[c] * W1[c * 128 + j];
            s_p1[hf][j] = v;
        }
        __syncthreads();
        if (tid < 128) {
            float vv = s_p1[0][tid] + s_p1[1][tid];
            float q1 = vv, q2 = vv * vv;
            #pragma unroll
            for (int m = 1; m < 64; m <<= 1) { q1 += __shfl_xor(q1, m); q2 += __shfl_xor(q2, m); }
            if ((tid & 63) == 0) { s_red[(tid >> 6) * 2] = q1; s_red[(tid >> 6) * 2 + 1] = q2; }
        }
        __syncthreads();
        if (tid < 128) {
            float sum1 = s_red[0] + s_red[2], sum2 = s_red[1] + s_red[3];
            float mean = sum1 * (1.f / 128.f);
            float var = sum2 * (1.f / 128.f) - mean * mean;
            float vv = s_p1[0][tid] + s_p1[1][tid];
            s_h1[tid] = fmaxf((vv - mean) * rsqrtf(var + 1e-5f) * g1[tid] + bt1[tid], 0.f);
        }
        __syncthreads();

        // W2: 128x64, split-K over 4 quarters
        {
            int j = tid & 63, q = tid >> 6;
            float v = (q == 0) ? b2[j] : 0.f;
            for (int c = q * 32; c < q * 32 + 32; ++c)
                v += s_h1[c] * W2[c * 64 + j];
            s_p2[q][j] = v;
        }
        __syncthreads();
        if (tid < 64) {
            float vv = s_p2[0][tid] + s_p2[1][tid] + s_p2[2][tid] + s_p2[3][tid];
            float q1 = vv, q2 = vv * vv;
            #pragma unroll
            for (int m = 1; m < 64; m <<= 1) { q1 += __shfl_xor(q1, m); q2 += __shfl_xor(q2, m); }
            float mean = q1 * (1.f / 64.f);
            float var = q2 * (1.f / 64.f) - mean * mean;
            s_h2[tid] = fmaxf((vv - mean) * rsqrtf(var + 1e-5f) * g2[tid] + bt2[tid], 0.f);
        }
        __syncthreads();

        if (hd == 0) {
            if (tid < 8) {
                float v3 = bo[tid];
                for (int c = 0; c < 64; ++c) v3 += s_h2[c] * Wo[c * 8 + tid];
                dout[(size_t)b * 8 + tid] = v3;
            }
        } else {
            if (tid == 0) {
                float v3 = bo[0];
                for (int c = 0; c < 64; ++c) v3 += s_h2[c] * Wo[c];
                dout[(size_t)BB * 8 + b] = v3;
            }
        }
        __syncthreads();
    }
}

extern "C" void kernel_launch(void* const* d_in, const int* in_sizes, int n_in,
                              void* d_out, int out_size, void* d_ws, size_t ws_size,
                              hipStream_t stream) {
    (void)in_sizes; (void)n_in; (void)out_size; (void)ws_size;
    const float* selfF  = (const float*)d_in[0];
    const float* nbF    = (const float*)d_in[1];
    const float* mask   = (const float*)d_in[2];
    const float* projW  = (const float*)d_in[3];
    const float* projB  = (const float*)d_in[4];
    const float* projG  = (const float*)d_in[5];
    const float* projBt = (const float*)d_in[6];
    const float* coopW  = (const float*)d_in[7];
    const float* coopS  = (const float*)d_in[8];
    const float* coopD  = (const float*)d_in[9];
    const float* confW  = (const float*)d_in[10];
    const float* confS  = (const float*)d_in[11];
    const float* confD  = (const float*)d_in[12];
    const float* sageW  = (const float*)d_in[13];
    const float* sageB  = (const float*)d_in[14];
    const float* gfWx = (const float*)d_in[15];
    const float* gfWh = (const float*)d_in[16];
    const float* gfbx = (const float*)d_in[17];
    const float* gfbh = (const float*)d_in[18];
    const float* gbWx = (const float*)d_in[19];
    const float* gbWh = (const float*)d_in[20];
    const float* gbbx = (const float*)d_in[21];
    const float* gbbh = (const float*)d_in[22];
    const float* pW1  = (const float*)d_in[23];
    const float* pb1  = (const float*)d_in[24];
    const float* pg1  = (const float*)d_in[25];
    const float* pbt1 = (const float*)d_in[26];
    const float* pW2  = (const float*)d_in[27];
    const float* pb2  = (const float*)d_in[28];
    const float* pg2  = (const float*)d_in[29];
    const float* pbt2 = (const float*)d_in[30];
    const float* pWo  = (const float*)d_in[31];
    const float* pbo  = (const float*)d_in[32];
    const float* vW1  = (const float*)d_in[33];
    const float* vb1  = (const float*)d_in[34];
    const float* vg1  = (const float*)d_in[35];
    const float* vbt1 = (const float*)d_in[36];
    const float* vW2  = (const float*)d_in[37];
    const float* vb2  = (const float*)d_in[38];
    const float* vg2  = (const float*)d_in[39];
    const float* vbt2 = (const float*)d_in[40];
    const float* vWo  = (const float*)d_in[41];
    const float* vbo  = (const float*)d_in[42];

    float* hsage   = (float*)d_ws;                              // B*T*64
    float* embLast = hsage + (size_t)BB * TT * SAGE_H;          // B*256

    gat_sage_kernel<<<BB * TT, 256, 0, stream>>>(
        selfF, nbF, mask, projW, projB, projG, projBt,
        coopW, coopS, coopD, confW, confS, confD,
        sageW, sageB, hsage, embLast);

    gru_head_kernel<<<BB, 256, 0, stream>>>(
        hsage, embLast,
        gfWx, gfWh, gfbx, gfbh, gbWx, gbWh, gbbx, gbbh,
        pW1, pb1, pg1, pbt1, pW2, pb2, pg2, pbt2, pWo, pbo,
        vW1, vb1, vg1, vbt1, vW2, vb2, vg2, vbt2, vWo, vbo,
        (float*)d_out);
}

// Round 3
// 1935.064 us; speedup vs baseline: 4.6346x; 4.6346x over previous
//
#include <hip/hip_runtime.h>
#include <math.h>

#define BB 4096
#define TT 5
#define KK 4
#define NLANES 12
#define GH 64
#define GO 32
#define GAT_TOT 256
#define SAGE_H 64
#define GRU_H 32

// ---------------------------------------------------------------------------
// Kernel A: per (b,t) block. All 5 instances (self + 4 neighbors) batched:
// proj+LN for all 60 rows, one Wh pass with acc[60] in registers (weights
// streamed from L1 inside the f-loop -- nothing persistent to spill), then
// per-instance attention/softmax/pool, agg + central-node SAGE row.
// ---------------------------------------------------------------------------
__global__ __launch_bounds__(256, 2) void gat_sage_kernel(
    const float* __restrict__ selfF, const float* __restrict__ nbF,
    const float* __restrict__ mask,
    const float* __restrict__ projW, const float* __restrict__ projB,
    const float* __restrict__ projG, const float* __restrict__ projBt,
    const float* __restrict__ coopW, const float* __restrict__ coopSrc, const float* __restrict__ coopDst,
    const float* __restrict__ confW, const float* __restrict__ confSrc, const float* __restrict__ confDst,
    const float* __restrict__ sageW, const float* __restrict__ sageB,
    float* __restrict__ hsage, float* __restrict__ embLast)
{
    __shared__ __align__(16) float s_x[5 * 48];
    __shared__ __align__(16) float s_h[60][GH];       // 15 KB
    __shared__ float s_sd[2][8][NLANES];
    __shared__ float s_att[8][NLANES][NLANES];
    __shared__ float s_pool[5][GAT_TOT];
    __shared__ float s_in[2 * GAT_TOT];
    __shared__ float s_part[4][SAGE_H];

    const int bid = blockIdx.x;          // b*T + t
    const int b = bid / TT, t = bid % TT;
    const int tid = threadIdx.x;

    const int gh = tid >> 5, o = tid & 31;     // thread owns (gat,head,o)
    const int g = gh >> 2, hh = gh & 3;

    // ---- load all 5 instances' inputs ----
    if (tid < 60) {
        int inst = tid / 12, j = tid % 12;
        const float* xp = (inst == 0)
            ? (selfF + (size_t)bid * 48)
            : (nbF + (size_t)((b * KK + (inst - 1)) * TT + t) * 48);
        ((float4*)s_x)[tid] = ((const float4*)xp)[j];
    }

    // proj row in registers (wave wv, lane = feature f)
    const int wv = tid >> 6, f = tid & 63;
    const float pw0 = projW[0 * GH + f], pw1 = projW[1 * GH + f];
    const float pw2 = projW[2 * GH + f], pw3 = projW[3 * GH + f];
    const float pb = projB[f], pg = projG[f], pbt = projBt[f];
    __syncthreads();

    // ---- proj + LN + relu for all 60 rows; wave wv does rows wv, wv+4, ... ----
    for (int i = 0; i < 15; ++i) {
        int r = wv + i * 4;
        float v = fmaf(s_x[r * 4 + 0], pw0, fmaf(s_x[r * 4 + 1], pw1,
                  fmaf(s_x[r * 4 + 2], pw2, fmaf(s_x[r * 4 + 3], pw3, pb))));
        float s1 = v, s2 = v * v;
        #pragma unroll
        for (int m = 1; m < 64; m <<= 1) {
            s1 += __shfl_xor(s1, m);
            s2 += __shfl_xor(s2, m);
        }
        float mean = s1 * (1.f / 64.f);
        float var  = s2 * (1.f / 64.f) - mean * mean;
        float nv = (v - mean) * rsqrtf(var + 1e-5f) * pg + pbt;
        s_h[r][f] = fmaxf(nv, 0.f);
    }
    __syncthreads();

    // ---- Wh for all 60 rows: acc[r] = sum_f h[r][f] * W[f][o] ----
    float acc[60];
    #pragma unroll
    for (int r = 0; r < 60; ++r) acc[r] = 0.f;
    {
        const float* Wp = (g ? confW : coopW) + hh * (GH * GO) + o;
        #pragma unroll 1
        for (int fc = 0; fc < 16; ++fc) {
            float w0 = Wp[(fc * 4 + 0) * GO];
            float w1 = Wp[(fc * 4 + 1) * GO];
            float w2 = Wp[(fc * 4 + 2) * GO];
            float w3 = Wp[(fc * 4 + 3) * GO];
            #pragma unroll
            for (int r = 0; r < 60; ++r) {
                float4 h4 = *(const float4*)&s_h[r][fc * 4];
                acc[r] = fmaf(h4.x, w0, fmaf(h4.y, w1,
                         fmaf(h4.z, w2, fmaf(h4.w, w3, acc[r]))));
            }
        }
    }

    const float a_s = (g ? confSrc : coopSrc)[hh * GO + o];
    const float a_d = (g ? confDst : coopDst)[hh * GO + o];

    // ---- per-instance attention + softmax + out/pool (inst static) ----
    #pragma unroll
    for (int inst = 0; inst < 5; ++inst) {
        {
            float sp[NLANES], dp[NLANES];
            #pragma unroll
            for (int n = 0; n < NLANES; ++n) {
                sp[n] = acc[inst * 12 + n] * a_s;
                dp[n] = acc[inst * 12 + n] * a_d;
            }
            #pragma unroll
            for (int m = 1; m < 32; m <<= 1) {
                #pragma unroll
                for (int n = 0; n < NLANES; ++n) {
                    sp[n] += __shfl_xor(sp[n], m);
                    dp[n] += __shfl_xor(dp[n], m);
                }
            }
            if (o == 0) {
                #pragma unroll
                for (int n = 0; n < NLANES; ++n) {
                    s_sd[0][gh][n] = sp[n];
                    s_sd[1][gh][n] = dp[n];
                }
            }
        }
        __syncthreads();

        if (tid < 96) {
            int gh2 = tid / 12, n2 = tid % 12;
            int g2 = gh2 >> 2;
            int an = n2 / 3;
            float sn = s_sd[0][gh2][n2];
            float e[NLANES];
            float mx = -1e30f;
            #pragma unroll
            for (int m2 = 0; m2 < NLANES; ++m2) {
                int am = m2 / 3;
                bool valid = (g2 == 0) ? (am == an) : (am != an || m2 == n2);
                if (valid) {
                    float ev = sn + s_sd[1][gh2][m2];
                    ev = ev > 0.f ? ev : 0.2f * ev;
                    e[m2] = ev;
                    mx = fmaxf(mx, ev);
                } else e[m2] = -1e30f;
            }
            float sum = 0.f;
            #pragma unroll
            for (int m2 = 0; m2 < NLANES; ++m2) {
                float ex = (e[m2] > -1e29f) ? __expf(e[m2] - mx) : 0.f;
                e[m2] = ex; sum += ex;
            }
            float inv = 1.f / sum;
            #pragma unroll
            for (int m2 = 0; m2 < NLANES; ++m2) s_att[gh2][n2][m2] = e[m2] * inv;
        }
        __syncthreads();

        {
            float pooled = 0.f;
            #pragma unroll
            for (int n = 0; n < NLANES; ++n) {
                float v = 0.f;
                #pragma unroll
                for (int m2 = 0; m2 < NLANES; ++m2)
                    v += s_att[gh][n][m2] * acc[inst * 12 + m2];
                v = v > 0.f ? v : (__expf(v) - 1.f);
                pooled += v;
            }
            s_pool[inst][tid] = pooled * (1.f / 12.f);
        }
        __syncthreads();
    }

    // ---- agg (masked mean) + concat ----
    {
        float m0 = mask[b * KK + 0], m1 = mask[b * KK + 1];
        float m2 = mask[b * KK + 2], m3 = mask[b * KK + 3];
        float inv = 1.f / fmaxf(m0 + m1 + m2 + m3, 1.f);
        s_in[tid] = s_pool[0][tid];
        s_in[GAT_TOT + tid] = (m0 * s_pool[1][tid] + m1 * s_pool[2][tid]
                             + m2 * s_pool[3][tid] + m3 * s_pool[4][tid]) * inv;
    }
    __syncthreads();

    // ---- central-node GraphSAGE row: split-K over 4 groups ----
    {
        int j = tid & 63, q = tid >> 6;
        float v = 0.f;
        for (int c = q * 128; c < q * 128 + 128; ++c)
            v += s_in[c] * sageW[c * SAGE_H + j];
        s_part[q][j] = v;
    }
    __syncthreads();
    if (tid < SAGE_H) {
        float v = sageB[tid] + s_part[0][tid] + s_part[1][tid]
                + s_part[2][tid] + s_part[3][tid];
        hsage[(size_t)bid * SAGE_H + tid] = fmaxf(v, 0.f);
    }
    if (t == TT - 1) embLast[(size_t)b * GAT_TOT + tid] = s_pool[0][tid];
}

// ---------------------------------------------------------------------------
// Kernel B: per-b block, 256 threads. Parallel gx precompute, serial h-part
// only, split-K MLP heads with shuffle LN.
// ---------------------------------------------------------------------------
__global__ __launch_bounds__(256) void gru_head_kernel(
    const float* __restrict__ hsage, const float* __restrict__ embLast,
    const float* __restrict__ gfWx, const float* __restrict__ gfWh,
    const float* __restrict__ gfbx, const float* __restrict__ gfbh,
    const float* __restrict__ gbWx, const float* __restrict__ gbWh,
    const float* __restrict__ gbbx, const float* __restrict__ gbbh,
    const float* __restrict__ pW1, const float* __restrict__ pb1,
    const float* __restrict__ pg1, const float* __restrict__ pbt1,
    const float* __restrict__ pW2, const float* __restrict__ pb2,
    const float* __restrict__ pg2, const float* __restrict__ pbt2,
    const float* __restrict__ pWo, const float* __restrict__ pbo,
    const float* __restrict__ vW1, const float* __restrict__ vb1,
    const float* __restrict__ vg1, const float* __restrict__ vbt1,
    const float* __restrict__ vW2, const float* __restrict__ vb2,
    const float* __restrict__ vg2, const float* __restrict__ vbt2,
    const float* __restrict__ vWo, const float* __restrict__ vbo,
    float* __restrict__ dout)
{
    __shared__ float s_seq[TT * SAGE_H];
    __shared__ float s_gx[2][TT][96];
    __shared__ float s_hh[2][GRU_H];
    __shared__ float s_joint[320];
    __shared__ float s_h1[128];
    __shared__ float s_h2[64];
    __shared__ float s_p1[2][128];
    __shared__ float s_p2[4][64];
    __shared__ float s_red[4];

    const int b = blockIdx.x, tid = threadIdx.x;

    for (int i = tid; i < TT * SAGE_H; i += 256) s_seq[i] = hsage[(size_t)b * TT * SAGE_H + i];
    s_joint[tid] = embLast[(size_t)b * GAT_TOT + tid];
    if (tid < 64) s_hh[tid >> 5][tid & 31] = 0.f;
    __syncthreads();

    for (int task = tid; task < 960; task += 256) {
        int dir = task >= 480;
        int rem = task - dir * 480;
        int t5 = rem / 96, j = rem - t5 * 96;
        const float* Wx = dir ? gbWx : gfWx;
        const float* bx = dir ? gbbx : gfbx;
        const float* x = &s_seq[t5 * SAGE_H];
        float v = bx[j];
        for (int f2 = 0; f2 < SAGE_H; ++f2) v += x[f2] * Wx[f2 * 96 + j];
        s_gx[dir][t5][j] = v;
    }
    __syncthreads();

    for (int s = 0; s < TT; ++s) {
        float hnew = 0.f;
        if (tid < 64) {
            int dir = tid >> 5, j = tid & 31;
            int t5 = dir ? (TT - 1 - s) : s;
            const float* Wh = dir ? gbWh : gfWh;
            const float* bh = dir ? gbbh : gfbh;
            const float* h = s_hh[dir];
            float hr = bh[j], hz = bh[32 + j], hn = bh[64 + j];
            for (int k = 0; k < GRU_H; ++k) {
                float hv = h[k];
                hr += hv * Wh[k * 96 + j];
                hz += hv * Wh[k * 96 + 32 + j];
                hn += hv * Wh[k * 96 + 64 + j];
            }
            float xr = s_gx[dir][t5][j], xz = s_gx[dir][t5][32 + j], xn = s_gx[dir][t5][64 + j];
            float r = 1.f / (1.f + __expf(-(xr + hr)));
            float z = 1.f / (1.f + __expf(-(xz + hz)));
            float nn = tanhf(xn + r * hn);
            hnew = (1.f - z) * nn + z * h[j];
        }
        __syncthreads();
        if (tid < 64) s_hh[tid >> 5][tid & 31] = hnew;
        __syncthreads();
    }
    if (tid < 64) s_joint[GAT_TOT + tid] = s_hh[tid >> 5][tid & 31];
    __syncthreads();

    for (int hd = 0; hd < 2; ++hd) {
        const float* W1 = hd ? vW1 : pW1;  const float* b1 = hd ? vb1 : pb1;
        const float* g1 = hd ? vg1 : pg1;  const float* bt1 = hd ? vbt1 : pbt1;
        const float* W2 = hd ? vW2 : pW2;  const float* b2 = hd ? vb2 : pb2;
        const float* g2 = hd ? vg2 : pg2;  const float* bt2 = hd ? vbt2 : pbt2;
        const float* Wo = hd ? vWo : pWo;  const float* bo = hd ? vbo : pbo;

        {
            int j = tid & 127, hf = tid >> 7;
            float v = (hf == 0) ? b1[j] : 0.f;
            for (int c = hf * 160; c < hf * 160 + 160; ++c)
                v += s_joint[c] * W1[c * 128 + j];
            s_p1[hf][j] = v;
        }
        __syncthreads();
        if (tid < 128) {
            float vv = s_p1[0][tid] + s_p1[1][tid];
            float q1 = vv, q2 = vv * vv;
            #pragma unroll
            for (int m = 1; m < 64; m <<= 1) { q1 += __shfl_xor(q1, m); q2 += __shfl_xor(q2, m); }
            if ((tid & 63) == 0) { s_red[(tid >> 6) * 2] = q1; s_red[(tid >> 6) * 2 + 1] = q2; }
        }
        __syncthreads();
        if (tid < 128) {
            float sum1 = s_red[0] + s_red[2], sum2 = s_red[1] + s_red[3];
            float mean = sum1 * (1.f / 128.f);
            float var = sum2 * (1.f / 128.f) - mean * mean;
            float vv = s_p1[0][tid] + s_p1[1][tid];
            s_h1[tid] = fmaxf((vv - mean) * rsqrtf(var + 1e-5f) * g1[tid] + bt1[tid], 0.f);
        }
        __syncthreads();

        {
            int j = tid & 63, q = tid >> 6;
            float v = (q == 0) ? b2[j] : 0.f;
            for (int c = q * 32; c < q * 32 + 32; ++c)
                v += s_h1[c] * W2[c * 64 + j];
            s_p2[q][j] = v;
        }
        __syncthreads();
        if (tid < 64) {
            float vv = s_p2[0][tid] + s_p2[1][tid] + s_p2[2][tid] + s_p2[3][tid];
            float q1 = vv, q2 = vv * vv;
            #pragma unroll
            for (int m = 1; m < 64; m <<= 1) { q1 += __shfl_xor(q1, m); q2 += __shfl_xor(q2, m); }
            float mean = q1 * (1.f / 64.f);
            float var = q2 * (1.f / 64.f) - mean * mean;
            s_h2[tid] = fmaxf((vv - mean) * rsqrtf(var + 1e-5f) * g2[tid] + bt2[tid], 0.f);
        }
        __syncthreads();

        if (hd == 0) {
            if (tid < 8) {
                float v3 = bo[tid];
                for (int c = 0; c < 64; ++c) v3 += s_h2[c] * Wo[c * 8 + tid];
                dout[(size_t)b * 8 + tid] = v3;
            }
        } else {
            if (tid == 0) {
                float v3 = bo[0];
                for (int c = 0; c < 64; ++c) v3 += s_h2[c] * Wo[c];
                dout[(size_t)BB * 8 + b] = v3;
            }
        }
        __syncthreads();
    }
}

extern "C" void kernel_launch(void* const* d_in, const int* in_sizes, int n_in,
                              void* d_out, int out_size, void* d_ws, size_t ws_size,
                              hipStream_t stream) {
    (void)in_sizes; (void)n_in; (void)out_size; (void)ws_size;
    const float* selfF  = (const float*)d_in[0];
    const float* nbF    = (const float*)d_in[1];
    const float* mask   = (const float*)d_in[2];
    const float* projW  = (const float*)d_in[3];
    const float* projB  = (const float*)d_in[4];
    const float* projG  = (const float*)d_in[5];
    const float* projBt = (const float*)d_in[6];
    const float* coopW  = (const float*)d_in[7];
    const float* coopS  = (const float*)d_in[8];
    const float* coopD  = (const float*)d_in[9];
    const float* confW  = (const float*)d_in[10];
    const float* confS  = (const float*)d_in[11];
    const float* confD  = (const float*)d_in[12];
    const float* sageW  = (const float*)d_in[13];
    const float* sageB  = (const float*)d_in[14];
    const float* gfWx = (const float*)d_in[15];
    const float* gfWh = (const float*)d_in[16];
    const float* gfbx = (const float*)d_in[17];
    const float* gfbh = (const float*)d_in[18];
    const float* gbWx = (const float*)d_in[19];
    const float* gbWh = (const float*)d_in[20];
    const float* gbbx = (const float*)d_in[21];
    const float* gbbh = (const float*)d_in[22];
    const float* pW1  = (const float*)d_in[23];
    const float* pb1  = (const float*)d_in[24];
    const float* pg1  = (const float*)d_in[25];
    const float* pbt1 = (const float*)d_in[26];
    const float* pW2  = (const float*)d_in[27];
    const float* pb2  = (const float*)d_in[28];
    const float* pg2  = (const float*)d_in[29];
    const float* pbt2 = (const float*)d_in[30];
    const float* pWo  = (const float*)d_in[31];
    const float* pbo  = (const float*)d_in[32];
    const float* vW1  = (const float*)d_in[33];
    const float* vb1  = (const float*)d_in[34];
    const float* vg1  = (const float*)d_in[35];
    const float* vbt1 = (const float*)d_in[36];
    const float* vW2  = (const float*)d_in[37];
    const float* vb2  = (const float*)d_in[38];
    const float* vg2  = (const float*)d_in[39];
    const float* vbt2 = (const float*)d_in[40];
    const float* vWo  = (const float*)d_in[41];
    const float* vbo  = (const float*)d_in[42];

    float* hsage   = (float*)d_ws;                              // B*T*64
    float* embLast = hsage + (size_t)BB * TT * SAGE_H;          // B*256

    gat_sage_kernel<<<BB * TT, 256, 0, stream>>>(
        selfF, nbF, mask, projW, projB, projG, projBt,
        coopW, coopS, coopD, confW, confS, confD,
        sageW, sageB, hsage, embLast);

    gru_head_kernel<<<BB, 256, 0, stream>>>(
        hsage, embLast,
        gfWx, gfWh, gfbx, gfbh, gbWx, gbWh, gbbx, gbbh,
        pW1, pb1, pg1, pbt1, pW2, pb2, pg2, pbt2, pWo, pbo,
        vW1, vb1, vg1, vbt1, vW2, vb2, vg2, vbt2, vWo, vbo,
        (float*)d_out);
}

// Round 4
// 1372.172 us; speedup vs baseline: 6.5358x; 1.4102x over previous
//
#include <hip/hip_runtime.h>
#include <math.h>

#define BB 4096
#define TT 5
#define KK 4
#define NLANES 12
#define GH 64
#define GO 32
#define GAT_TOT 256
#define SAGE_H 64
#define GRU_H 32

typedef __attribute__((ext_vector_type(8))) short short8v;
typedef __attribute__((ext_vector_type(8))) unsigned short ushort8v;
typedef __attribute__((ext_vector_type(4))) unsigned short ushort4v;
typedef __attribute__((ext_vector_type(4))) float f32x4;

__device__ __forceinline__ unsigned short f2bf(float x) {
    unsigned u = __float_as_uint(x);
    u += 0x7fffu + ((u >> 16) & 1u);
    return (unsigned short)(u >> 16);
}
__device__ __forceinline__ float bf2f(unsigned short b) {
    return __uint_as_float(((unsigned)b) << 16);
}

// ---------------------------------------------------------------------------
// Setup: W^T bf16 [256 cols][64 k] from coopW/confW ([4][64][32] each).
// col c = g*128 + hh*32 + o; value = W_g[hh][k][o].
// ---------------------------------------------------------------------------
__global__ void wt_setup_kernel(const float* __restrict__ coopW,
                                const float* __restrict__ confW,
                                unsigned short* __restrict__ wt) {
    int c = threadIdx.x;                 // 256 threads, one col each
    int g = c >> 7, hh = (c >> 5) & 3, o = c & 31;
    const float* W = (g ? confW : coopW) + hh * (GH * GO) + o;
    for (int k = 0; k < GH; ++k)
        wt[c * GH + k] = f2bf(W[k * GO]);
}

// ---------------------------------------------------------------------------
// Kernel A: per (b,t) block. proj+LN (f32, shuffle LN) -> h bf16 swizzled in
// LDS -> MFMA Wh GEMM (64x64x256) -> Wh^T bf16 LDS -> per-thread acc[60]
// readback -> round-3 attention/softmax/pool/sage (unchanged).
// ---------------------------------------------------------------------------
__global__ __launch_bounds__(256, 3) void gat_sage_kernel(
    const float* __restrict__ selfF, const float* __restrict__ nbF,
    const float* __restrict__ mask,
    const float* __restrict__ projW, const float* __restrict__ projB,
    const float* __restrict__ projG, const float* __restrict__ projBt,
    const float* __restrict__ coopSrc, const float* __restrict__ coopDst,
    const float* __restrict__ confSrc, const float* __restrict__ confDst,
    const unsigned short* __restrict__ wt,
    const float* __restrict__ sageW, const float* __restrict__ sageB,
    float* __restrict__ hsage, float* __restrict__ embLast)
{
    __shared__ __align__(16) float s_x[5 * 48];
    __shared__ __align__(16) unsigned short s_hb[64 * 64];   // 8 KB swizzled bf16
    __shared__ __align__(16) char s_dyn[32768];              // WhT | att/pool/in/part
    __shared__ float s_sd[2][8][NLANES];

    unsigned short* WhT = (unsigned short*)s_dyn;                      // [256][64] bf16 swz
    float (*s_att)[NLANES][NLANES] = (float (*)[NLANES][NLANES])s_dyn; // [8][12][12]
    float (*s_pool)[GAT_TOT] = (float (*)[GAT_TOT])(s_dyn + 4608);     // [5][256]
    float* s_in = (float*)(s_dyn + 4608 + 5120);                       // [512]
    float (*s_part)[SAGE_H] = (float (*)[SAGE_H])(s_dyn + 4608 + 5120 + 2048); // [4][64]

    const int bid = blockIdx.x;          // b*T + t
    const int b = bid / TT, t = bid % TT;
    const int tid = threadIdx.x;

    const int gh = tid >> 5, o = tid & 31;     // thread owns (gat,head,o)
    const int g = gh >> 2, hh = gh & 3;
    const int wv = tid >> 6, f = tid & 63;     // wave, lane
    const int l15 = f & 15, g4 = f >> 4;

    // ---- load all 5 instances' inputs ----
    if (tid < 60) {
        int inst = tid / 12, j = tid % 12;
        const float* xp = (inst == 0)
            ? (selfF + (size_t)bid * 48)
            : (nbF + (size_t)((b * KK + (inst - 1)) * TT + t) * 48);
        ((float4*)s_x)[tid] = ((const float4*)xp)[j];
    }

    // proj row in registers (lane = feature f)
    const float pw0 = projW[0 * GH + f], pw1 = projW[1 * GH + f];
    const float pw2 = projW[2 * GH + f], pw3 = projW[3 * GH + f];
    const float pb = projB[f], pg = projG[f], pbt = projBt[f];
    __syncthreads();

    // ---- proj + LN + relu; wave wv does rows wv, wv+4, ..., wv+56 ----
    #pragma unroll
    for (int i = 0; i < 15; ++i) {
        const int r = wv + i * 4;
        float v = fmaf(s_x[r * 4 + 0], pw0, fmaf(s_x[r * 4 + 1], pw1,
                  fmaf(s_x[r * 4 + 2], pw2, fmaf(s_x[r * 4 + 3], pw3, pb))));
        float s1 = v, s2 = v * v;
        #pragma unroll
        for (int m = 1; m < 64; m <<= 1) {
            s1 += __shfl_xor(s1, m);
            s2 += __shfl_xor(s2, m);
        }
        float mean = s1 * (1.f / 64.f);
        float var  = s2 * (1.f / 64.f) - mean * mean;
        float nv = (v - mean) * rsqrtf(var + 1e-5f) * pg + pbt;
        nv = fmaxf(nv, 0.f);
        // swizzled bf16 write: chunk = (f>>3) ^ (r&7)
        s_hb[r * 64 + (((f >> 3) ^ (r & 7)) << 3) + (f & 7)] = f2bf(nv);
    }
    {   // zero-pad rows 60..63 (wave wv -> row 60+wv)
        const int r = 60 + wv;
        s_hb[r * 64 + (((f >> 3) ^ (r & 7)) << 3) + (f & 7)] = 0;
    }
    __syncthreads();

    // ---- GEMM1: Wh = h[64x64] @ W[64x256], wave wv owns cols [64wv,64wv+64) ----
    {
        f32x4 c[4][4];
        #pragma unroll
        for (int mt = 0; mt < 4; ++mt)
            #pragma unroll
            for (int nt = 0; nt < 4; ++nt)
                c[mt][nt] = (f32x4){0.f, 0.f, 0.f, 0.f};

        #pragma unroll
        for (int kt = 0; kt < 2; ++kt) {
            const int kc = kt * 4 + g4;
            short8v a[4], bfr[4];
            #pragma unroll
            for (int mt = 0; mt < 4; ++mt) {
                const int r = mt * 16 + l15;
                a[mt] = *(const short8v*)&s_hb[r * 64 + ((kc ^ (r & 7)) << 3)];
            }
            #pragma unroll
            for (int nt = 0; nt < 4; ++nt) {
                const int cc = wv * 64 + nt * 16 + l15;
                bfr[nt] = *(const short8v*)&wt[cc * 64 + (kc << 3)];
            }
            #pragma unroll
            for (int mt = 0; mt < 4; ++mt)
                #pragma unroll
                for (int nt = 0; nt < 4; ++nt)
                    c[mt][nt] = __builtin_amdgcn_mfma_f32_16x16x32_bf16(
                        a[mt], bfr[nt], c[mt][nt], 0, 0, 0);
        }

        // ---- pack C frags -> WhT bf16 [col][64 rows], swizzled rows ----
        #pragma unroll
        for (int mt = 0; mt < 4; ++mt) {
            #pragma unroll
            for (int nt = 0; nt < 4; ++nt) {
                const int cc = wv * 64 + nt * 16 + l15;
                const int rb = mt * 16 + g4 * 4;           // 4 consecutive rows
                ushort4v p;
                p.x = f2bf(c[mt][nt].x); p.y = f2bf(c[mt][nt].y);
                p.z = f2bf(c[mt][nt].z); p.w = f2bf(c[mt][nt].w);
                const int idx = cc * 64 + (((rb >> 3) ^ (cc & 7)) << 3) + (rb & 7);
                *(ushort4v*)&WhT[idx] = p;
            }
        }
    }
    __syncthreads();

    // ---- readback: acc[r] = Wh[r][col=tid] (wave reads its own rows) ----
    float acc[60];
    {
        const int cs = tid & 7;
        #pragma unroll
        for (int ch = 0; ch < 8; ++ch) {
            ushort8v v = *(const ushort8v*)&WhT[tid * 64 + ((ch ^ cs) << 3)];
            #pragma unroll
            for (int j = 0; j < 8; ++j) {
                const int r = ch * 8 + j;
                if (r < 60) acc[r] = bf2f(v[j]);
            }
        }
    }
    __syncthreads();   // WhT dead; s_att/s_pool region live from here

    const float a_s = (g ? confSrc : coopSrc)[hh * GO + o];
    const float a_d = (g ? confDst : coopDst)[hh * GO + o];

    // ---- per-instance attention + softmax + out/pool (round-3 code) ----
    #pragma unroll
    for (int inst = 0; inst < 5; ++inst) {
        {
            float sp[NLANES], dp[NLANES];
            #pragma unroll
            for (int n = 0; n < NLANES; ++n) {
                sp[n] = acc[inst * 12 + n] * a_s;
                dp[n] = acc[inst * 12 + n] * a_d;
            }
            #pragma unroll
            for (int m = 1; m < 32; m <<= 1) {
                #pragma unroll
                for (int n = 0; n < NLANES; ++n) {
                    sp[n] += __shfl_xor(sp[n], m);
                    dp[n] += __shfl_xor(dp[n], m);
                }
            }
            if (o == 0) {
                #pragma unroll
                for (int n = 0; n < NLANES; ++n) {
                    s_sd[0][gh][n] = sp[n];
                    s_sd[1][gh][n] = dp[n];
                }
            }
        }
        __syncthreads();

        if (tid < 96) {
            int gh2 = tid / 12, n2 = tid % 12;
            int g2 = gh2 >> 2;
            int an = n2 / 3;
            float sn = s_sd[0][gh2][n2];
            float e[NLANES];
            float mx = -1e30f;
            #pragma unroll
            for (int m2 = 0; m2 < NLANES; ++m2) {
                int am = m2 / 3;
                bool valid = (g2 == 0) ? (am == an) : (am != an || m2 == n2);
                if (valid) {
                    float ev = sn + s_sd[1][gh2][m2];
                    ev = ev > 0.f ? ev : 0.2f * ev;
                    e[m2] = ev;
                    mx = fmaxf(mx, ev);
                } else e[m2] = -1e30f;
            }
            float sum = 0.f;
            #pragma unroll
            for (int m2 = 0; m2 < NLANES; ++m2) {
                float ex = (e[m2] > -1e29f) ? __expf(e[m2] - mx) : 0.f;
                e[m2] = ex; sum += ex;
            }
            float inv = 1.f / sum;
            #pragma unroll
            for (int m2 = 0; m2 < NLANES; ++m2) s_att[gh2][n2][m2] = e[m2] * inv;
        }
        __syncthreads();

        {
            float pooled = 0.f;
            #pragma unroll
            for (int n = 0; n < NLANES; ++n) {
                float v = 0.f;
                #pragma unroll
                for (int m2 = 0; m2 < NLANES; ++m2)
                    v += s_att[gh][n][m2] * acc[inst * 12 + m2];
                v = v > 0.f ? v : (__expf(v) - 1.f);
                pooled += v;
            }
            s_pool[inst][tid] = pooled * (1.f / 12.f);
        }
        __syncthreads();
    }

    // ---- agg (masked mean) + concat ----
    {
        float m0 = mask[b * KK + 0], m1 = mask[b * KK + 1];
        float m2 = mask[b * KK + 2], m3 = mask[b * KK + 3];
        float inv = 1.f / fmaxf(m0 + m1 + m2 + m3, 1.f);
        s_in[tid] = s_pool[0][tid];
        s_in[GAT_TOT + tid] = (m0 * s_pool[1][tid] + m1 * s_pool[2][tid]
                             + m2 * s_pool[3][tid] + m3 * s_pool[4][tid]) * inv;
    }
    __syncthreads();

    // ---- central-node GraphSAGE row: split-K over 4 groups ----
    {
        int j = tid & 63, q = tid >> 6;
        float v = 0.f;
        for (int c = q * 128; c < q * 128 + 128; ++c)
            v += s_in[c] * sageW[c * SAGE_H + j];
        s_part[q][j] = v;
    }
    __syncthreads();
    if (tid < SAGE_H) {
        float v = sageB[tid] + s_part[0][tid] + s_part[1][tid]
                + s_part[2][tid] + s_part[3][tid];
        hsage[(size_t)bid * SAGE_H + tid] = fmaxf(v, 0.f);
    }
    if (t == TT - 1) embLast[(size_t)b * GAT_TOT + tid] = s_pool[0][tid];
}

// ---------------------------------------------------------------------------
// Kernel B: per-b block, 256 threads (unchanged from round 3).
// ---------------------------------------------------------------------------
__global__ __launch_bounds__(256) void gru_head_kernel(
    const float* __restrict__ hsage, const float* __restrict__ embLast,
    const float* __restrict__ gfWx, const float* __restrict__ gfWh,
    const float* __restrict__ gfbx, const float* __restrict__ gfbh,
    const float* __restrict__ gbWx, const float* __restrict__ gbWh,
    const float* __restrict__ gbbx, const float* __restrict__ gbbh,
    const float* __restrict__ pW1, const float* __restrict__ pb1,
    const float* __restrict__ pg1, const float* __restrict__ pbt1,
    const float* __restrict__ pW2, const float* __restrict__ pb2,
    const float* __restrict__ pg2, const float* __restrict__ pbt2,
    const float* __restrict__ pWo, const float* __restrict__ pbo,
    const float* __restrict__ vW1, const float* __restrict__ vb1,
    const float* __restrict__ vg1, const float* __restrict__ vbt1,
    const float* __restrict__ vW2, const float* __restrict__ vb2,
    const float* __restrict__ vg2, const float* __restrict__ vbt2,
    const float* __restrict__ vWo, const float* __restrict__ vbo,
    float* __restrict__ dout)
{
    __shared__ float s_seq[TT * SAGE_H];
    __shared__ float s_gx[2][TT][96];
    __shared__ float s_hh[2][GRU_H];
    __shared__ float s_joint[320];
    __shared__ float s_h1[128];
    __shared__ float s_h2[64];
    __shared__ float s_p1[2][128];
    __shared__ float s_p2[4][64];
    __shared__ float s_red[4];

    const int b = blockIdx.x, tid = threadIdx.x;

    for (int i = tid; i < TT * SAGE_H; i += 256) s_seq[i] = hsage[(size_t)b * TT * SAGE_H + i];
    s_joint[tid] = embLast[(size_t)b * GAT_TOT + tid];
    if (tid < 64) s_hh[tid >> 5][tid & 31] = 0.f;
    __syncthreads();

    for (int task = tid; task < 960; task += 256) {
        int dir = task >= 480;
        int rem = task - dir * 480;
        int t5 = rem / 96, j = rem - t5 * 96;
        const float* Wx = dir ? gbWx : gfWx;
        const float* bx = dir ? gbbx : gfbx;
        const float* x = &s_seq[t5 * SAGE_H];
        float v = bx[j];
        for (int f2 = 0; f2 < SAGE_H; ++f2) v += x[f2] * Wx[f2 * 96 + j];
        s_gx[dir][t5][j] = v;
    }
    __syncthreads();

    for (int s = 0; s < TT; ++s) {
        float hnew = 0.f;
        if (tid < 64) {
            int dir = tid >> 5, j = tid & 31;
            int t5 = dir ? (TT - 1 - s) : s;
            const float* Wh = dir ? gbWh : gfWh;
            const float* bh = dir ? gbbh : gfbh;
            const float* h = s_hh[dir];
            float hr = bh[j], hz = bh[32 + j], hn = bh[64 + j];
            for (int k = 0; k < GRU_H; ++k) {
                float hv = h[k];
                hr += hv * Wh[k * 96 + j];
                hz += hv * Wh[k * 96 + 32 + j];
                hn += hv * Wh[k * 96 + 64 + j];
            }
            float xr = s_gx[dir][t5][j], xz = s_gx[dir][t5][32 + j], xn = s_gx[dir][t5][64 + j];
            float r = 1.f / (1.f + __expf(-(xr + hr)));
            float z = 1.f / (1.f + __expf(-(xz + hz)));
            float nn = tanhf(xn + r * hn);
            hnew = (1.f - z) * nn + z * h[j];
        }
        __syncthreads();
        if (tid < 64) s_hh[tid >> 5][tid & 31] = hnew;
        __syncthreads();
    }
    if (tid < 64) s_joint[GAT_TOT + tid] = s_hh[tid >> 5][tid & 31];
    __syncthreads();

    for (int hd = 0; hd < 2; ++hd) {
        const float* W1 = hd ? vW1 : pW1;  const float* b1 = hd ? vb1 : pb1;
        const float* g1 = hd ? vg1 : pg1;  const float* bt1 = hd ? vbt1 : pbt1;
        const float* W2 = hd ? vW2 : pW2;  const float* b2 = hd ? vb2 : pb2;
        const float* g2 = hd ? vg2 : pg2;  const float* bt2 = hd ? vbt2 : pbt2;
        const float* Wo = hd ? vWo : pWo;  const float* bo = hd ? vbo : pbo;

        {
            int j = tid & 127, hf = tid >> 7;
            float v = (hf == 0) ? b1[j] : 0.f;
            for (int c = hf * 160; c < hf * 160 + 160; ++c)
                v += s_joint[c] * W1[c * 128 + j];
            s_p1[hf][j] = v;
        }
        __syncthreads();
        if (tid < 128) {
            float vv = s_p1[0][tid] + s_p1[1][tid];
            float q1 = vv, q2 = vv * vv;
            #pragma unroll
            for (int m = 1; m < 64; m <<= 1) { q1 += __shfl_xor(q1, m); q2 += __shfl_xor(q2, m); }
            if ((tid & 63) == 0) { s_red[(tid >> 6) * 2] = q1; s_red[(tid >> 6) * 2 + 1] = q2; }
        }
        __syncthreads();
        if (tid < 128) {
            float sum1 = s_red[0] + s_red[2], sum2 = s_red[1] + s_red[3];
            float mean = sum1 * (1.f / 128.f);
            float var = sum2 * (1.f / 128.f) - mean * mean;
            float vv = s_p1[0][tid] + s_p1[1][tid];
            s_h1[tid] = fmaxf((vv - mean) * rsqrtf(var + 1e-5f) * g1[tid] + bt1[tid], 0.f);
        }
        __syncthreads();

        {
            int j = tid & 63, q = tid >> 6;
            float v = (q == 0) ? b2[j] : 0.f;
            for (int c = q * 32; c < q * 32 + 32; ++c)
                v += s_h1[c] * W2[c * 64 + j];
            s_p2[q][j] = v;
        }
        __syncthreads();
        if (tid < 64) {
            float vv = s_p2[0][tid] + s_p2[1][tid] + s_p2[2][tid] + s_p2[3][tid];
            float q1 = vv, q2 = vv * vv;
            #pragma unroll
            for (int m = 1; m < 64; m <<= 1) { q1 += __shfl_xor(q1, m); q2 += __shfl_xor(q2, m); }
            float mean = q1 * (1.f / 64.f);
            float var = q2 * (1.f / 64.f) - mean * mean;
            s_h2[tid] = fmaxf((vv - mean) * rsqrtf(var + 1e-5f) * g2[tid] + bt2[tid], 0.f);
        }
        __syncthreads();

        if (hd == 0) {
            if (tid < 8) {
                float v3 = bo[tid];
                for (int c = 0; c < 64; ++c) v3 += s_h2[c] * Wo[c * 8 + tid];
                dout[(size_t)b * 8 + tid] = v3;
            }
        } else {
            if (tid == 0) {
                float v3 = bo[0];
                for (int c = 0; c < 64; ++c) v3 += s_h2[c] * Wo[c];
                dout[(size_t)BB * 8 + b] = v3;
            }
        }
        __syncthreads();
    }
}

extern "C" void kernel_launch(void* const* d_in, const int* in_sizes, int n_in,
                              void* d_out, int out_size, void* d_ws, size_t ws_size,
                              hipStream_t stream) {
    (void)in_sizes; (void)n_in; (void)out_size; (void)ws_size;
    const float* selfF  = (const float*)d_in[0];
    const float* nbF    = (const float*)d_in[1];
    const float* mask   = (const float*)d_in[2];
    const float* projW  = (const float*)d_in[3];
    const float* projB  = (const float*)d_in[4];
    const float* projG  = (const float*)d_in[5];
    const float* projBt = (const float*)d_in[6];
    const float* coopW  = (const float*)d_in[7];
    const float* coopS  = (const float*)d_in[8];
    const float* coopD  = (const float*)d_in[9];
    const float* confW  = (const float*)d_in[10];
    const float* confS  = (const float*)d_in[11];
    const float* confD  = (const float*)d_in[12];
    const float* sageW  = (const float*)d_in[13];
    const float* sageB  = (const float*)d_in[14];
    const float* gfWx = (const float*)d_in[15];
    const float* gfWh = (const float*)d_in[16];
    const float* gfbx = (const float*)d_in[17];
    const float* gfbh = (const float*)d_in[18];
    const float* gbWx = (const float*)d_in[19];
    const float* gbWh = (const float*)d_in[20];
    const float* gbbx = (const float*)d_in[21];
    const float* gbbh = (const float*)d_in[22];
    const float* pW1  = (const float*)d_in[23];
    const float* pb1  = (const float*)d_in[24];
    const float* pg1  = (const float*)d_in[25];
    const float* pbt1 = (const float*)d_in[26];
    const float* pW2  = (const float*)d_in[27];
    const float* pb2  = (const float*)d_in[28];
    const float* pg2  = (const float*)d_in[29];
    const float* pbt2 = (const float*)d_in[30];
    const float* pWo  = (const float*)d_in[31];
    const float* pbo  = (const float*)d_in[32];
    const float* vW1  = (const float*)d_in[33];
    const float* vb1  = (const float*)d_in[34];
    const float* vg1  = (const float*)d_in[35];
    const float* vbt1 = (const float*)d_in[36];
    const float* vW2  = (const float*)d_in[37];
    const float* vb2  = (const float*)d_in[38];
    const float* vg2  = (const float*)d_in[39];
    const float* vbt2 = (const float*)d_in[40];
    const float* vWo  = (const float*)d_in[41];
    const float* vbo  = (const float*)d_in[42];

    float* hsage   = (float*)d_ws;                                    // B*T*64 f32
    float* embLast = hsage + (size_t)BB * TT * SAGE_H;                // B*256 f32
    unsigned short* wt = (unsigned short*)(embLast + (size_t)BB * GAT_TOT); // [256][64] bf16

    wt_setup_kernel<<<1, 256, 0, stream>>>(coopW, confW, wt);

    gat_sage_kernel<<<BB * TT, 256, 0, stream>>>(
        selfF, nbF, mask, projW, projB, projG, projBt,
        coopS, coopD, confS, confD, wt,
        sageW, sageB, hsage, embLast);

    gru_head_kernel<<<BB, 256, 0, stream>>>(
        hsage, embLast,
        gfWx, gfWh, gfbx, gfbh, gbWx, gbWh, gbbx, gbbh,
        pW1, pb1, pg1, pbt1, pW2, pb2, pg2, pbt2, pWo, pbo,
        vW1, vb1, vg1, vbt1, vW2, vb2, vg2, vbt2, vWo, vbo,
        (float*)d_out);
}